// Round 8
// baseline (130.956 us; speedup 1.0000x reference)
//
#include <hip/hip_runtime.h>
#include <math.h>

#define LNEPS 1e-5f

typedef short bf16x8 __attribute__((ext_vector_type(8)));
typedef float f32x4 __attribute__((ext_vector_type(4)));

__device__ __forceinline__ unsigned short f2bf(float f) {
    union { float f; unsigned int u; } v; v.f = f;
    unsigned int r = v.u + 0x7fffu + ((v.u >> 16) & 1u);
    return (unsigned short)(r >> 16);
}

__device__ __forceinline__ float bf2f(unsigned short u) {
    union { unsigned int i; float f; } v;
    v.i = ((unsigned int)u) << 16;
    return v.f;
}

__device__ __forceinline__ void block_ln_stats(float v, int tid, float* red,
                                               float& mu, float& rs) {
    float s = v, ss = v * v;
#pragma unroll
    for (int off = 32; off; off >>= 1) {
        s += __shfl_xor(s, off);
        ss += __shfl_xor(ss, off);
    }
    if ((tid & 63) == 0) { red[tid >> 6] = s; red[4 + (tid >> 6)] = ss; }
    __syncthreads();
    s = red[0] + red[1] + red[2] + red[3];
    ss = red[4] + red[5] + red[6] + red[7];
    mu = s * (1.0f / 256.0f);
    float var = ss * (1.0f / 256.0f) - mu * mu;
    rs = rsqrtf(var + LNEPS);
}

__device__ __forceinline__ float gelu_exact(float v) {
    return 0.5f * v * (1.0f + erff(v * 0.70710678118654752f));
}

// ---------- kATT: [kA 8-tok: LN_mia + V=xn@Wv ->bf16] + [W1,W2 transp->bf16] + [Wo->bf16]
__global__ __launch_bounds__(256) void kATT(const float* __restrict__ x,
                                            const float* __restrict__ g,
                                            const float* __restrict__ be,
                                            const float* __restrict__ Wv,
                                            unsigned short* __restrict__ Vb,
                                            const float* __restrict__ W1,
                                            unsigned short* __restrict__ W1t,
                                            const float* __restrict__ W2,
                                            unsigned short* __restrict__ W2t,
                                            const float* __restrict__ Wo,
                                            unsigned short* __restrict__ Wob) {
    __shared__ float smem[4096];
    const int bid = blockIdx.x, tid = threadIdx.x;
    if (bid < 512) {
        float* sx = smem;           // [8][256]
        float* part = smem + 2048;  // [4][8][64]
        const int t0 = bid * 8;
        {
            const int r = tid >> 5, lc = tid & 31;
            const float* xr = x + (size_t)(t0 + r) * 256 + lc * 8;
            float vv[8];
            *(float4*)&vv[0] = *(const float4*)xr;
            *(float4*)&vv[4] = *(const float4*)(xr + 4);
            float s = 0.f, ss = 0.f;
#pragma unroll
            for (int i = 0; i < 8; ++i) { s += vv[i]; ss = fmaf(vv[i], vv[i], ss); }
#pragma unroll
            for (int off = 16; off; off >>= 1) {
                s += __shfl_xor(s, off, 32);
                ss += __shfl_xor(ss, off, 32);
            }
            float mu = s * (1.0f / 256.0f);
            float var = ss * (1.0f / 256.0f) - mu * mu;
            float rs = rsqrtf(var + LNEPS);
            const int c0 = lc * 8;
            float o[8];
#pragma unroll
            for (int i = 0; i < 8; ++i)
                o[i] = (vv[i] - mu) * rs * g[c0 + i] + be[c0 + i];
            *(float4*)&sx[r * 256 + c0] = *(float4*)&o[0];
            *(float4*)&sx[r * 256 + c0 + 4] = *(float4*)&o[4];
        }
        __syncthreads();
        const int c = tid & 63, q = tid >> 6;
        float p[8] = {};
        const float* wp = Wv + (size_t)(q * 64) * 64 + c;
        const float* sxp = sx + q * 64;
#pragma unroll 8
        for (int d = 0; d < 64; ++d) {
            float wv = wp[(size_t)d * 64];
#pragma unroll
            for (int r = 0; r < 8; ++r) p[r] = fmaf(sxp[r * 256 + d], wv, p[r]);
        }
#pragma unroll
        for (int r = 0; r < 8; ++r) part[(q * 8 + r) * 64 + c] = p[r];
        __syncthreads();
        const int rr = tid >> 6;
#pragma unroll
        for (int rw = rr; rw < 8; rw += 4) {
            float sum = part[(0 * 8 + rw) * 64 + c] + part[(1 * 8 + rw) * 64 + c] +
                        part[(2 * 8 + rw) * 64 + c] + part[(3 * 8 + rw) * 64 + c];
            Vb[(size_t)(t0 + rw) * 64 + c] = f2bf(sum);
        }
    } else if (bid < 1024) {
        int b = bid - 512;
        const float* W;
        unsigned short* Wt;
        int K, N, n0, k0;
        if (b < 256) { W = W1; Wt = W1t; K = 256; N = 1024; n0 = (b & 31) * 32; k0 = (b >> 5) * 32; }
        else { b -= 256; W = W2; Wt = W2t; K = 1024; N = 256; n0 = (b & 7) * 32; k0 = (b >> 3) * 32; }
        float(*s)[33] = (float(*)[33])smem;
        const int cl = tid & 31, rq = tid >> 5;
#pragma unroll
        for (int i = 0; i < 4; ++i)
            s[rq * 4 + i][cl] = W[(size_t)(k0 + rq * 4 + i) * N + n0 + cl];
        __syncthreads();
#pragma unroll
        for (int i = 0; i < 4; ++i)
            Wt[(size_t)(n0 + rq * 4 + i) * K + k0 + cl] = f2bf(s[cl][rq * 4 + i]);
    } else {
        int i = ((bid - 1024) * 256 + tid) * 8;
        float4 a = *(const float4*)&Wo[i];
        float4 d = *(const float4*)&Wo[i + 4];
        ushort4 o1, o2;
        o1.x = f2bf(a.x); o1.y = f2bf(a.y); o1.z = f2bf(a.z); o1.w = f2bf(a.w);
        o2.x = f2bf(d.x); o2.y = f2bf(d.y); o2.z = f2bf(d.z); o2.w = f2bf(d.w);
        *(ushort4*)&Wob[i] = o1;
        *(ushort4*)&Wob[i + 4] = o2;
    }
}

// ---------- kernel B: no-max softmax MIA + @Wo + residual + LN_ffn ----------
// Pure function of (x,U1,mask,Vb,Wob,...) -> (out, xn2b); overwrites fully.
// Launched TWICE this round as a timing probe (idempotent).
__global__ __launch_bounds__(256) void kB(const float* __restrict__ x,
                                          const float4* __restrict__ U4,
                                          const int* __restrict__ mask,
                                          const ushort4* __restrict__ V4b,
                                          const unsigned short* __restrict__ Wob,
                                          const float* __restrict__ gf,
                                          const float* __restrict__ bf,
                                          const float* __restrict__ b2,
                                          float* __restrict__ out,
                                          unsigned short* __restrict__ xn2b) {
    __shared__ float sl[16][64], al[16][64];
    __shared__ float mia[64];
    __shared__ float red[8];
    __shared__ float mkf[256];
    const int token = blockIdx.x, tid = threadIdx.x;
    const int b = token >> 8;
    const int l16 = tid & 15, jo = tid >> 4;
    mkf[tid] = (mask[b * 256 + tid] != 0) ? 1.0f : 0.0f;
    __syncthreads();

    float s0 = 0, s1 = 0, s2 = 0, s3 = 0;
    float a0 = 0, a1 = 0, a2 = 0, a3 = 0;
    const size_t ub = (size_t)token * (256 * 16);
    const size_t vb = (size_t)b * (256 * 16);
#pragma unroll 8
    for (int j = jo; j < 256; j += 16) {
        float4 u = U4[ub + (size_t)j * 16 + l16];
        ushort4 vv4 = V4b[vb + (size_t)j * 16 + l16];
        float mw = mkf[j];
        float w;
        w = __expf(u.x) * mw; s0 += w; a0 = fmaf(w, bf2f(vv4.x), a0);
        w = __expf(u.y) * mw; s1 += w; a1 = fmaf(w, bf2f(vv4.y), a1);
        w = __expf(u.z) * mw; s2 += w; a2 = fmaf(w, bf2f(vv4.z), a2);
        w = __expf(u.w) * mw; s3 += w; a3 = fmaf(w, bf2f(vv4.w), a3);
    }
    sl[jo][l16 * 4 + 0] = s0; sl[jo][l16 * 4 + 1] = s1;
    sl[jo][l16 * 4 + 2] = s2; sl[jo][l16 * 4 + 3] = s3;
    al[jo][l16 * 4 + 0] = a0; al[jo][l16 * 4 + 1] = a1;
    al[jo][l16 * 4 + 2] = a2; al[jo][l16 * 4 + 3] = a3;
    __syncthreads();
    if (tid < 64) {
        float S = 0, A = 0;
#pragma unroll
        for (int p = 0; p < 16; ++p) { S += sl[p][tid]; A += al[p][tid]; }
        mia[tid] = A / S;
    }
    __syncthreads();

    float r = x[(size_t)token * 256 + tid];
#pragma unroll 8
    for (int c = 0; c < 64; ++c)
        r = fmaf(mia[c], bf2f(Wob[(size_t)c * 256 + tid]), r);
    out[(size_t)token * 256 + tid] = r + b2[tid];
    float mu, rs;
    block_ln_stats(r, tid, red, mu, rs);
    xn2b[(size_t)token * 256 + tid] = f2bf((r - mu) * rs * gf[tid] + bf[tid]);
}

// ---------- kC2m: Aact = gelu(xn2b @ W1 + b1), bf16 MFMA, BK=64 ----------
__global__ __launch_bounds__(256) void kC2m(const unsigned short* __restrict__ A,
                                            const unsigned short* __restrict__ Bt,
                                            const float* __restrict__ b1,
                                            unsigned short* __restrict__ Aact) {
    __shared__ __align__(16) unsigned short As[128][72];
    __shared__ __align__(16) unsigned short Bs[64][72];
    const int tid = threadIdx.x;
    const int tileM = blockIdx.y * 128, tileN = blockIdx.x * 64;
    const int w = tid >> 6, lane = tid & 63;
    const int waveM = w >> 1, waveN = w & 1;
    const int fr = lane & 15, fg = lane >> 4;
    f32x4 acc[4][2] = {};
    for (int kc = 0; kc < 256; kc += 64) {
#pragma unroll
        for (int h = 0; h < 4; ++h) {
            int idx = tid + h * 256;
            int row = idx >> 3, seg = idx & 7;
            *(uint4*)&As[row][seg * 8] =
                *(const uint4*)&A[(size_t)(tileM + row) * 256 + kc + seg * 8];
        }
#pragma unroll
        for (int h = 0; h < 2; ++h) {
            int idx = tid + h * 256;
            int row = idx >> 3, seg = idx & 7;
            *(uint4*)&Bs[row][seg * 8] =
                *(const uint4*)&Bt[(size_t)(tileN + row) * 256 + kc + seg * 8];
        }
        __syncthreads();
        bf16x8 a[4][2], b[2][2];
#pragma unroll
        for (int m = 0; m < 4; ++m)
#pragma unroll
            for (int k = 0; k < 2; ++k)
                a[m][k] = *(const bf16x8*)&As[waveM * 64 + m * 16 + fr][k * 32 + fg * 8];
#pragma unroll
        for (int n = 0; n < 2; ++n)
#pragma unroll
            for (int k = 0; k < 2; ++k)
                b[n][k] = *(const bf16x8*)&Bs[waveN * 32 + n * 16 + fr][k * 32 + fg * 8];
#pragma unroll
        for (int k = 0; k < 2; ++k)
#pragma unroll
            for (int m = 0; m < 4; ++m)
#pragma unroll
                for (int n = 0; n < 2; ++n)
                    acc[m][n] = __builtin_amdgcn_mfma_f32_16x16x32_bf16(
                        a[m][k], b[n][k], acc[m][n], 0, 0, 0);
        __syncthreads();
    }
#pragma unroll
    for (int m = 0; m < 4; ++m)
#pragma unroll
        for (int n = 0; n < 2; ++n) {
            int col = tileN + waveN * 32 + n * 16 + fr;
            float bb = b1[col];
#pragma unroll
            for (int r = 0; r < 4; ++r) {
                int row = tileM + waveM * 64 + m * 16 + fg * 4 + r;
                float v = acc[m][n][r] + bb;
                Aact[(size_t)row * 1024 + col] = f2bf(gelu_exact(v));
            }
        }
}

// ---------- kC3n: out += Aact @ W2, in-block split-K (8 waves), no atomics ----------
__global__ __launch_bounds__(512) void kC3n(const unsigned short* __restrict__ A,
                                            const unsigned short* __restrict__ Bt,
                                            float* __restrict__ out) {
    __shared__ __align__(16) unsigned short sAB[2][2][64][72];  // 36864 B
    const int tid = threadIdx.x;
    const int w = tid >> 6, lane = tid & 63;
    const int kz = w >> 2, q = w & 3;
    const int waveM = q >> 1, waveN = q & 1;
    const int fr = lane & 15, fg = lane >> 4;
    const int tl = tid & 255;
    const int tileM = blockIdx.x * 64, tileN = blockIdx.y * 64;
    unsigned short(*As)[72] = sAB[kz][0];
    unsigned short(*Bs)[72] = sAB[kz][1];
    f32x4 acc[2][2] = {};
    for (int t = 0; t < 8; ++t) {
        const int kc = kz * 512 + t * 64;
#pragma unroll
        for (int h = 0; h < 2; ++h) {
            int idx = tl + h * 256;
            int row = idx >> 3, seg = idx & 7;
            *(uint4*)&As[row][seg * 8] =
                *(const uint4*)&A[(size_t)(tileM + row) * 1024 + kc + seg * 8];
        }
#pragma unroll
        for (int h = 0; h < 2; ++h) {
            int idx = tl + h * 256;
            int row = idx >> 3, seg = idx & 7;
            *(uint4*)&Bs[row][seg * 8] =
                *(const uint4*)&Bt[(size_t)(tileN + row) * 1024 + kc + seg * 8];
        }
        __syncthreads();
        bf16x8 a[2][2], b[2][2];
#pragma unroll
        for (int m = 0; m < 2; ++m)
#pragma unroll
            for (int k = 0; k < 2; ++k)
                a[m][k] = *(const bf16x8*)&As[waveM * 32 + m * 16 + fr][k * 32 + fg * 8];
#pragma unroll
        for (int n = 0; n < 2; ++n)
#pragma unroll
            for (int k = 0; k < 2; ++k)
                b[n][k] = *(const bf16x8*)&Bs[waveN * 32 + n * 16 + fr][k * 32 + fg * 8];
#pragma unroll
        for (int k = 0; k < 2; ++k)
#pragma unroll
            for (int m = 0; m < 2; ++m)
#pragma unroll
                for (int n = 0; n < 2; ++n)
                    acc[m][n] = __builtin_amdgcn_mfma_f32_16x16x32_bf16(
                        a[m][k], b[n][k], acc[m][n], 0, 0, 0);
        __syncthreads();
    }
    // reduce the two K-halves via LDS (reuse staging memory), single-owner store
    float* sred = (float*)&sAB[0][0][0][0];  // 64*64 f32 = 16 KB < 36 KB
    if (kz == 1) {
#pragma unroll
        for (int m = 0; m < 2; ++m)
#pragma unroll
            for (int n = 0; n < 2; ++n) {
                int col = waveN * 32 + n * 16 + fr;
#pragma unroll
                for (int r = 0; r < 4; ++r) {
                    int row = waveM * 32 + m * 16 + fg * 4 + r;
                    sred[row * 64 + col] = acc[m][n][r];
                }
            }
    }
    __syncthreads();
    if (kz == 0) {
#pragma unroll
        for (int m = 0; m < 2; ++m)
#pragma unroll
            for (int n = 0; n < 2; ++n) {
                int col = waveN * 32 + n * 16 + fr;
#pragma unroll
                for (int r = 0; r < 4; ++r) {
                    int row = waveM * 32 + m * 16 + fg * 4 + r;
                    size_t idx = (size_t)(tileM + row) * 256 + tileN + col;
                    out[idx] += acc[m][n][r] + sred[row * 64 + col];
                }
            }
    }
}

extern "C" void kernel_launch(void* const* d_in, const int* in_sizes, int n_in,
                              void* d_out, int out_size, void* d_ws, size_t ws_size,
                              hipStream_t stream) {
    const float* x = (const float*)d_in[0];
    const float* U1 = (const float*)d_in[1];
    const int* mask = (const int*)d_in[2];
    const float* ln_mia_g = (const float*)d_in[3];
    const float* ln_mia_b = (const float*)d_in[4];
    const float* Wv = (const float*)d_in[5];
    const float* Wo = (const float*)d_in[6];
    const float* ln_ffn_g = (const float*)d_in[7];
    const float* ln_ffn_b = (const float*)d_in[8];
    const float* W1 = (const float*)d_in[9];
    const float* b1 = (const float*)d_in[10];
    const float* W2 = (const float*)d_in[11];
    const float* b2 = (const float*)d_in[12];
    float* out = (float*)d_out;

    char* ws = (char*)d_ws;
    unsigned short* Vb   = (unsigned short*)(ws);                             // 512 KB
    unsigned short* xn2b = (unsigned short*)(ws + (1u << 20));                // 2 MB
    unsigned short* W1t  = (unsigned short*)(ws + (3u << 20));                // 512 KB
    unsigned short* W2t  = (unsigned short*)(ws + (3u << 20) + (512u << 10)); // 512 KB
    unsigned short* Wob  = (unsigned short*)(ws + (4u << 20));                // 32 KB
    unsigned short* Aact = (unsigned short*)(ws + (5u << 20));                // 8 MB

    kATT<<<1032, 256, 0, stream>>>(x, ln_mia_g, ln_mia_b, Wv, Vb,
                                   W1, W1t, W2, W2t, Wo, Wob);
    // TIMING PROBE: kB launched twice (idempotent overwrite of out/xn2b).
    // dur(this round) - dur(round 7) ~= t_kB.
    kB<<<4096, 256, 0, stream>>>(x, (const float4*)U1, mask, (const ushort4*)Vb,
                                 Wob, ln_ffn_g, ln_ffn_b, b2, out, xn2b);
    kB<<<4096, 256, 0, stream>>>(x, (const float4*)U1, mask, (const ushort4*)Vb,
                                 Wob, ln_ffn_g, ln_ffn_b, b2, out, xn2b);
    kC2m<<<dim3(16, 32), 256, 0, stream>>>(xn2b, W1t, b1, Aact);
    kC3n<<<dim3(64, 4), 512, 0, stream>>>(Aact, W2t, out);
}

// Round 10
// 86.209 us; speedup vs baseline: 1.5191x; 1.5191x over previous
//
#include <hip/hip_runtime.h>
#include <math.h>

#define LNEPS 1e-5f

typedef short bf16x8 __attribute__((ext_vector_type(8)));
typedef float f32x4 __attribute__((ext_vector_type(4)));
typedef float f32x4v __attribute__((ext_vector_type(4)));

__device__ __forceinline__ unsigned short f2bf(float f) {
    union { float f; unsigned int u; } v; v.f = f;
    unsigned int r = v.u + 0x7fffu + ((v.u >> 16) & 1u);
    return (unsigned short)(r >> 16);
}

__device__ __forceinline__ float bf2f(unsigned short u) {
    union { unsigned int i; float f; } v;
    v.i = ((unsigned int)u) << 16;
    return v.f;
}

__device__ __forceinline__ void block_ln_stats(float v, int tid, float* red,
                                               float& mu, float& rs) {
    float s = v, ss = v * v;
#pragma unroll
    for (int off = 32; off; off >>= 1) {
        s += __shfl_xor(s, off);
        ss += __shfl_xor(ss, off);
    }
    if ((tid & 63) == 0) { red[tid >> 6] = s; red[4 + (tid >> 6)] = ss; }
    __syncthreads();
    s = red[0] + red[1] + red[2] + red[3];
    ss = red[4] + red[5] + red[6] + red[7];
    mu = s * (1.0f / 256.0f);
    float var = ss * (1.0f / 256.0f) - mu * mu;
    rs = rsqrtf(var + LNEPS);
}

__device__ __forceinline__ float gelu_exact(float v) {
    return 0.5f * v * (1.0f + erff(v * 0.70710678118654752f));
}

// ---------- kATT: [kA 8-tok: LN_mia + V=xn@Wv ->bf16] + [W1,W2 transp->bf16] + [Wo->bf16]
__global__ __launch_bounds__(256) void kATT(const float* __restrict__ x,
                                            const float* __restrict__ g,
                                            const float* __restrict__ be,
                                            const float* __restrict__ Wv,
                                            unsigned short* __restrict__ Vb,
                                            const float* __restrict__ W1,
                                            unsigned short* __restrict__ W1t,
                                            const float* __restrict__ W2,
                                            unsigned short* __restrict__ W2t,
                                            const float* __restrict__ Wo,
                                            unsigned short* __restrict__ Wob) {
    __shared__ float smem[4096];
    const int bid = blockIdx.x, tid = threadIdx.x;
    if (bid < 512) {
        float* sx = smem;           // [8][256]
        float* part = smem + 2048;  // [4][8][64]
        const int t0 = bid * 8;
        {
            const int r = tid >> 5, lc = tid & 31;
            const float* xr = x + (size_t)(t0 + r) * 256 + lc * 8;
            float vv[8];
            *(float4*)&vv[0] = *(const float4*)xr;
            *(float4*)&vv[4] = *(const float4*)(xr + 4);
            float s = 0.f, ss = 0.f;
#pragma unroll
            for (int i = 0; i < 8; ++i) { s += vv[i]; ss = fmaf(vv[i], vv[i], ss); }
#pragma unroll
            for (int off = 16; off; off >>= 1) {
                s += __shfl_xor(s, off, 32);
                ss += __shfl_xor(ss, off, 32);
            }
            float mu = s * (1.0f / 256.0f);
            float var = ss * (1.0f / 256.0f) - mu * mu;
            float rs = rsqrtf(var + LNEPS);
            const int c0 = lc * 8;
            float o[8];
#pragma unroll
            for (int i = 0; i < 8; ++i)
                o[i] = (vv[i] - mu) * rs * g[c0 + i] + be[c0 + i];
            *(float4*)&sx[r * 256 + c0] = *(float4*)&o[0];
            *(float4*)&sx[r * 256 + c0 + 4] = *(float4*)&o[4];
        }
        __syncthreads();
        const int c = tid & 63, q = tid >> 6;
        float p[8] = {};
        const float* wp = Wv + (size_t)(q * 64) * 64 + c;
        const float* sxp = sx + q * 64;
#pragma unroll 8
        for (int d = 0; d < 64; ++d) {
            float wv = wp[(size_t)d * 64];
#pragma unroll
            for (int r = 0; r < 8; ++r) p[r] = fmaf(sxp[r * 256 + d], wv, p[r]);
        }
#pragma unroll
        for (int r = 0; r < 8; ++r) part[(q * 8 + r) * 64 + c] = p[r];
        __syncthreads();
        const int rr = tid >> 6;
#pragma unroll
        for (int rw = rr; rw < 8; rw += 4) {
            float sum = part[(0 * 8 + rw) * 64 + c] + part[(1 * 8 + rw) * 64 + c] +
                        part[(2 * 8 + rw) * 64 + c] + part[(3 * 8 + rw) * 64 + c];
            Vb[(size_t)(t0 + rw) * 64 + c] = f2bf(sum);
        }
    } else if (bid < 1024) {
        int b = bid - 512;
        const float* W;
        unsigned short* Wt;
        int K, N, n0, k0;
        if (b < 256) { W = W1; Wt = W1t; K = 256; N = 1024; n0 = (b & 31) * 32; k0 = (b >> 5) * 32; }
        else { b -= 256; W = W2; Wt = W2t; K = 1024; N = 256; n0 = (b & 7) * 32; k0 = (b >> 3) * 32; }
        float(*s)[33] = (float(*)[33])smem;
        const int cl = tid & 31, rq = tid >> 5;
#pragma unroll
        for (int i = 0; i < 4; ++i)
            s[rq * 4 + i][cl] = W[(size_t)(k0 + rq * 4 + i) * N + n0 + cl];
        __syncthreads();
#pragma unroll
        for (int i = 0; i < 4; ++i)
            Wt[(size_t)(n0 + rq * 4 + i) * K + k0 + cl] = f2bf(s[cl][rq * 4 + i]);
    } else {
        int i = ((bid - 1024) * 256 + tid) * 8;
        float4 a = *(const float4*)&Wo[i];
        float4 d = *(const float4*)&Wo[i + 4];
        ushort4 o1, o2;
        o1.x = f2bf(a.x); o1.y = f2bf(a.y); o1.z = f2bf(a.z); o1.w = f2bf(a.w);
        o2.x = f2bf(d.x); o2.y = f2bf(d.y); o2.z = f2bf(d.z); o2.w = f2bf(d.w);
        *(ushort4*)&Wob[i] = o1;
        *(ushort4*)&Wob[i + 4] = o2;
    }
}

// ---------- kernel B: no-max softmax MIA + @Wo + residual + LN_ffn ----------
// U1 loads non-temporal (clang ext-vector type required by the builtin):
// the single-use 268 MB stream must not evict V/x/Wo/mask from L2.
__global__ __launch_bounds__(256) void kB(const float* __restrict__ x,
                                          const f32x4v* __restrict__ U4,
                                          const int* __restrict__ mask,
                                          const ushort4* __restrict__ V4b,
                                          const unsigned short* __restrict__ Wob,
                                          const float* __restrict__ gf,
                                          const float* __restrict__ bf,
                                          const float* __restrict__ b2,
                                          float* __restrict__ out,
                                          unsigned short* __restrict__ xn2b) {
    __shared__ float sl[16][64], al[16][64];
    __shared__ float mia[64];
    __shared__ float red[8];
    __shared__ float mkf[256];
    const int token = blockIdx.x, tid = threadIdx.x;
    const int b = token >> 8;
    const int l16 = tid & 15, jo = tid >> 4;
    mkf[tid] = (mask[b * 256 + tid] != 0) ? 1.0f : 0.0f;
    __syncthreads();

    float s0 = 0, s1 = 0, s2 = 0, s3 = 0;
    float a0 = 0, a1 = 0, a2 = 0, a3 = 0;
    const size_t ub = (size_t)token * (256 * 16);
    const size_t vb = (size_t)b * (256 * 16);
#pragma unroll 4
    for (int j = jo; j < 256; j += 16) {
        f32x4v u = __builtin_nontemporal_load(&U4[ub + (size_t)j * 16 + l16]);
        ushort4 vv4 = V4b[vb + (size_t)j * 16 + l16];
        float mw = mkf[j];
        float w;
        w = __expf(u.x) * mw; s0 += w; a0 = fmaf(w, bf2f(vv4.x), a0);
        w = __expf(u.y) * mw; s1 += w; a1 = fmaf(w, bf2f(vv4.y), a1);
        w = __expf(u.z) * mw; s2 += w; a2 = fmaf(w, bf2f(vv4.z), a2);
        w = __expf(u.w) * mw; s3 += w; a3 = fmaf(w, bf2f(vv4.w), a3);
    }
    sl[jo][l16 * 4 + 0] = s0; sl[jo][l16 * 4 + 1] = s1;
    sl[jo][l16 * 4 + 2] = s2; sl[jo][l16 * 4 + 3] = s3;
    al[jo][l16 * 4 + 0] = a0; al[jo][l16 * 4 + 1] = a1;
    al[jo][l16 * 4 + 2] = a2; al[jo][l16 * 4 + 3] = a3;
    __syncthreads();
    if (tid < 64) {
        float S = 0, A = 0;
#pragma unroll
        for (int p = 0; p < 16; ++p) { S += sl[p][tid]; A += al[p][tid]; }
        mia[tid] = A / S;
    }
    __syncthreads();

    float r = x[(size_t)token * 256 + tid];
#pragma unroll 8
    for (int c = 0; c < 64; ++c)
        r = fmaf(mia[c], bf2f(Wob[(size_t)c * 256 + tid]), r);
    out[(size_t)token * 256 + tid] = r + b2[tid];
    float mu, rs;
    block_ln_stats(r, tid, red, mu, rs);
    xn2b[(size_t)token * 256 + tid] = f2bf((r - mu) * rs * gf[tid] + bf[tid]);
}

// ---------- kC2s: Aact = gelu(xn2b @ W1 + b1), 64x64 tile, 1024 blocks ----------
__global__ __launch_bounds__(256) void kC2s(const unsigned short* __restrict__ A,
                                            const unsigned short* __restrict__ Bt,
                                            const float* __restrict__ b1,
                                            unsigned short* __restrict__ Aact) {
    __shared__ __align__(16) unsigned short As[64][72];
    __shared__ __align__(16) unsigned short Bs[64][72];
    const int tid = threadIdx.x;
    const int tileM = blockIdx.y * 64, tileN = blockIdx.x * 64;
    const int w = tid >> 6, lane = tid & 63;
    const int waveM = w >> 1, waveN = w & 1;
    const int fr = lane & 15, fg = lane >> 4;
    f32x4 acc[2][2] = {};
    for (int kc = 0; kc < 256; kc += 64) {
#pragma unroll
        for (int h = 0; h < 2; ++h) {
            int idx = tid + h * 256;
            int row = idx >> 3, seg = idx & 7;
            *(uint4*)&As[row][seg * 8] =
                *(const uint4*)&A[(size_t)(tileM + row) * 256 + kc + seg * 8];
        }
#pragma unroll
        for (int h = 0; h < 2; ++h) {
            int idx = tid + h * 256;
            int row = idx >> 3, seg = idx & 7;
            *(uint4*)&Bs[row][seg * 8] =
                *(const uint4*)&Bt[(size_t)(tileN + row) * 256 + kc + seg * 8];
        }
        __syncthreads();
        bf16x8 a[2][2], b[2][2];
#pragma unroll
        for (int m = 0; m < 2; ++m)
#pragma unroll
            for (int k = 0; k < 2; ++k)
                a[m][k] = *(const bf16x8*)&As[waveM * 32 + m * 16 + fr][k * 32 + fg * 8];
#pragma unroll
        for (int n = 0; n < 2; ++n)
#pragma unroll
            for (int k = 0; k < 2; ++k)
                b[n][k] = *(const bf16x8*)&Bs[waveN * 32 + n * 16 + fr][k * 32 + fg * 8];
#pragma unroll
        for (int k = 0; k < 2; ++k)
#pragma unroll
            for (int m = 0; m < 2; ++m)
#pragma unroll
                for (int n = 0; n < 2; ++n)
                    acc[m][n] = __builtin_amdgcn_mfma_f32_16x16x32_bf16(
                        a[m][k], b[n][k], acc[m][n], 0, 0, 0);
        __syncthreads();
    }
#pragma unroll
    for (int m = 0; m < 2; ++m)
#pragma unroll
        for (int n = 0; n < 2; ++n) {
            int col = tileN + waveN * 32 + n * 16 + fr;
            float bb = b1[col];
#pragma unroll
            for (int r = 0; r < 4; ++r) {
                int row = tileM + waveM * 32 + m * 16 + fg * 4 + r;
                float v = acc[m][n][r] + bb;
                Aact[(size_t)row * 1024 + col] = f2bf(gelu_exact(v));
            }
        }
}

// ---------- kC3a: out += Aact @ W2 (split-K x2 across blocks, atomicAdd) ----------
__global__ __launch_bounds__(256) void kC3a(const unsigned short* __restrict__ A,
                                            const unsigned short* __restrict__ Bt,
                                            float* __restrict__ out) {
    __shared__ __align__(16) unsigned short As[64][72];
    __shared__ __align__(16) unsigned short Bs[64][72];
    const int tid = threadIdx.x;
    const int tileM = blockIdx.y * 64, tileN = blockIdx.x * 64;
    const int k0 = blockIdx.z * 512;
    const int w = tid >> 6, lane = tid & 63;
    const int waveM = w >> 1, waveN = w & 1;
    const int fr = lane & 15, fg = lane >> 4;
    f32x4 acc[2][2] = {};
    for (int kc = k0; kc < k0 + 512; kc += 64) {
#pragma unroll
        for (int h = 0; h < 2; ++h) {
            int idx = tid + h * 256;
            int row = idx >> 3, seg = idx & 7;
            *(uint4*)&As[row][seg * 8] =
                *(const uint4*)&A[(size_t)(tileM + row) * 1024 + kc + seg * 8];
        }
#pragma unroll
        for (int h = 0; h < 2; ++h) {
            int idx = tid + h * 256;
            int row = idx >> 3, seg = idx & 7;
            *(uint4*)&Bs[row][seg * 8] =
                *(const uint4*)&Bt[(size_t)(tileN + row) * 1024 + kc + seg * 8];
        }
        __syncthreads();
        bf16x8 a[2][2], b[2][2];
#pragma unroll
        for (int m = 0; m < 2; ++m)
#pragma unroll
            for (int k = 0; k < 2; ++k)
                a[m][k] = *(const bf16x8*)&As[waveM * 32 + m * 16 + fr][k * 32 + fg * 8];
#pragma unroll
        for (int n = 0; n < 2; ++n)
#pragma unroll
            for (int k = 0; k < 2; ++k)
                b[n][k] = *(const bf16x8*)&Bs[waveN * 32 + n * 16 + fr][k * 32 + fg * 8];
#pragma unroll
        for (int k = 0; k < 2; ++k)
#pragma unroll
            for (int m = 0; m < 2; ++m)
#pragma unroll
                for (int n = 0; n < 2; ++n)
                    acc[m][n] = __builtin_amdgcn_mfma_f32_16x16x32_bf16(
                        a[m][k], b[n][k], acc[m][n], 0, 0, 0);
        __syncthreads();
    }
#pragma unroll
    for (int m = 0; m < 2; ++m)
#pragma unroll
        for (int n = 0; n < 2; ++n) {
            int col = tileN + waveN * 32 + n * 16 + fr;
#pragma unroll
            for (int r = 0; r < 4; ++r) {
                int row = tileM + waveM * 32 + m * 16 + fg * 4 + r;
                atomicAdd(&out[(size_t)row * 256 + col], acc[m][n][r]);
            }
        }
}

extern "C" void kernel_launch(void* const* d_in, const int* in_sizes, int n_in,
                              void* d_out, int out_size, void* d_ws, size_t ws_size,
                              hipStream_t stream) {
    const float* x = (const float*)d_in[0];
    const float* U1 = (const float*)d_in[1];
    const int* mask = (const int*)d_in[2];
    const float* ln_mia_g = (const float*)d_in[3];
    const float* ln_mia_b = (const float*)d_in[4];
    const float* Wv = (const float*)d_in[5];
    const float* Wo = (const float*)d_in[6];
    const float* ln_ffn_g = (const float*)d_in[7];
    const float* ln_ffn_b = (const float*)d_in[8];
    const float* W1 = (const float*)d_in[9];
    const float* b1 = (const float*)d_in[10];
    const float* W2 = (const float*)d_in[11];
    const float* b2 = (const float*)d_in[12];
    float* out = (float*)d_out;

    char* ws = (char*)d_ws;
    unsigned short* Vb   = (unsigned short*)(ws);                             // 512 KB
    unsigned short* xn2b = (unsigned short*)(ws + (1u << 20));                // 2 MB
    unsigned short* W1t  = (unsigned short*)(ws + (3u << 20));                // 512 KB
    unsigned short* W2t  = (unsigned short*)(ws + (3u << 20) + (512u << 10)); // 512 KB
    unsigned short* Wob  = (unsigned short*)(ws + (4u << 20));                // 32 KB
    unsigned short* Aact = (unsigned short*)(ws + (5u << 20));                // 8 MB

    kATT<<<1032, 256, 0, stream>>>(x, ln_mia_g, ln_mia_b, Wv, Vb,
                                   W1, W1t, W2, W2t, Wo, Wob);
    kB<<<4096, 256, 0, stream>>>(x, (const f32x4v*)U1, mask, (const ushort4*)Vb,
                                 Wob, ln_ffn_g, ln_ffn_b, b2, out, xn2b);
    kC2s<<<dim3(16, 64), 256, 0, stream>>>(xn2b, W1t, b1, Aact);
    kC3a<<<dim3(4, 64, 2), 256, 0, stream>>>(Aact, W2t, out);
}

// Round 12
// 83.504 us; speedup vs baseline: 1.5683x; 1.0324x over previous
//
#include <hip/hip_runtime.h>
#include <math.h>

#define LNEPS 1e-5f

typedef short bf16x8 __attribute__((ext_vector_type(8)));
typedef float f32x4 __attribute__((ext_vector_type(4)));

__device__ __forceinline__ unsigned short f2bf(float f) {
    union { float f; unsigned int u; } v; v.f = f;
    unsigned int r = v.u + 0x7fffu + ((v.u >> 16) & 1u);
    return (unsigned short)(r >> 16);
}

__device__ __forceinline__ float bf2f(unsigned short u) {
    union { unsigned int i; float f; } v;
    v.i = ((unsigned int)u) << 16;
    return v.f;
}

__device__ __forceinline__ void block_ln_stats(float v, int tid, float* red,
                                               float& mu, float& rs) {
    float s = v, ss = v * v;
#pragma unroll
    for (int off = 32; off; off >>= 1) {
        s += __shfl_xor(s, off);
        ss += __shfl_xor(ss, off);
    }
    if ((tid & 63) == 0) { red[tid >> 6] = s; red[4 + (tid >> 6)] = ss; }
    __syncthreads();
    s = red[0] + red[1] + red[2] + red[3];
    ss = red[4] + red[5] + red[6] + red[7];
    mu = s * (1.0f / 256.0f);
    float var = ss * (1.0f / 256.0f) - mu * mu;
    rs = rsqrtf(var + LNEPS);
}

__device__ __forceinline__ float gelu_exact(float v) {
    return 0.5f * v * (1.0f + erff(v * 0.70710678118654752f));
}

// ---------- kATT: [kA 8-tok: LN_mia + V=xn@Wv ->bf16] + [W1,W2 transp->bf16] + [Wo->bf16]
__global__ __launch_bounds__(256) void kATT(const float* __restrict__ x,
                                            const float* __restrict__ g,
                                            const float* __restrict__ be,
                                            const float* __restrict__ Wv,
                                            unsigned short* __restrict__ Vb,
                                            const float* __restrict__ W1,
                                            unsigned short* __restrict__ W1t,
                                            const float* __restrict__ W2,
                                            unsigned short* __restrict__ W2t,
                                            const float* __restrict__ Wo,
                                            unsigned short* __restrict__ Wob) {
    __shared__ float smem[4096];
    const int bid = blockIdx.x, tid = threadIdx.x;
    if (bid < 512) {
        float* sx = smem;           // [8][256]
        float* part = smem + 2048;  // [4][8][64]
        const int t0 = bid * 8;
        {
            const int r = tid >> 5, lc = tid & 31;
            const float* xr = x + (size_t)(t0 + r) * 256 + lc * 8;
            float vv[8];
            *(float4*)&vv[0] = *(const float4*)xr;
            *(float4*)&vv[4] = *(const float4*)(xr + 4);
            float s = 0.f, ss = 0.f;
#pragma unroll
            for (int i = 0; i < 8; ++i) { s += vv[i]; ss = fmaf(vv[i], vv[i], ss); }
#pragma unroll
            for (int off = 16; off; off >>= 1) {
                s += __shfl_xor(s, off, 32);
                ss += __shfl_xor(ss, off, 32);
            }
            float mu = s * (1.0f / 256.0f);
            float var = ss * (1.0f / 256.0f) - mu * mu;
            float rs = rsqrtf(var + LNEPS);
            const int c0 = lc * 8;
            float o[8];
#pragma unroll
            for (int i = 0; i < 8; ++i)
                o[i] = (vv[i] - mu) * rs * g[c0 + i] + be[c0 + i];
            *(float4*)&sx[r * 256 + c0] = *(float4*)&o[0];
            *(float4*)&sx[r * 256 + c0 + 4] = *(float4*)&o[4];
        }
        __syncthreads();
        const int c = tid & 63, q = tid >> 6;
        float p[8] = {};
        const float* wp = Wv + (size_t)(q * 64) * 64 + c;
        const float* sxp = sx + q * 64;
#pragma unroll 8
        for (int d = 0; d < 64; ++d) {
            float wv = wp[(size_t)d * 64];
#pragma unroll
            for (int r = 0; r < 8; ++r) p[r] = fmaf(sxp[r * 256 + d], wv, p[r]);
        }
#pragma unroll
        for (int r = 0; r < 8; ++r) part[(q * 8 + r) * 64 + c] = p[r];
        __syncthreads();
        const int rr = tid >> 6;
#pragma unroll
        for (int rw = rr; rw < 8; rw += 4) {
            float sum = part[(0 * 8 + rw) * 64 + c] + part[(1 * 8 + rw) * 64 + c] +
                        part[(2 * 8 + rw) * 64 + c] + part[(3 * 8 + rw) * 64 + c];
            Vb[(size_t)(t0 + rw) * 64 + c] = f2bf(sum);
        }
    } else if (bid < 1024) {
        int b = bid - 512;
        const float* W;
        unsigned short* Wt;
        int K, N, n0, k0;
        if (b < 256) { W = W1; Wt = W1t; K = 256; N = 1024; n0 = (b & 31) * 32; k0 = (b >> 5) * 32; }
        else { b -= 256; W = W2; Wt = W2t; K = 1024; N = 256; n0 = (b & 7) * 32; k0 = (b >> 3) * 32; }
        float(*s)[33] = (float(*)[33])smem;
        const int cl = tid & 31, rq = tid >> 5;
#pragma unroll
        for (int i = 0; i < 4; ++i)
            s[rq * 4 + i][cl] = W[(size_t)(k0 + rq * 4 + i) * N + n0 + cl];
        __syncthreads();
#pragma unroll
        for (int i = 0; i < 4; ++i)
            Wt[(size_t)(n0 + rq * 4 + i) * K + k0 + cl] = f2bf(s[cl][rq * 4 + i]);
    } else {
        int i = ((bid - 1024) * 256 + tid) * 8;
        float4 a = *(const float4*)&Wo[i];
        float4 d = *(const float4*)&Wo[i + 4];
        ushort4 o1, o2;
        o1.x = f2bf(a.x); o1.y = f2bf(a.y); o1.z = f2bf(a.z); o1.w = f2bf(a.w);
        o2.x = f2bf(d.x); o2.y = f2bf(d.y); o2.z = f2bf(d.z); o2.w = f2bf(d.w);
        *(ushort4*)&Wob[i] = o1;
        *(ushort4*)&Wob[i + 4] = o2;
    }
}

// ---------- kernel B: no-max softmax MIA + @Wo + residual + LN_ffn ----------
// (round-7 proven form: plain loads, unroll 8)
__global__ __launch_bounds__(256) void kB(const float* __restrict__ x,
                                          const float4* __restrict__ U4,
                                          const int* __restrict__ mask,
                                          const ushort4* __restrict__ V4b,
                                          const unsigned short* __restrict__ Wob,
                                          const float* __restrict__ gf,
                                          const float* __restrict__ bf,
                                          const float* __restrict__ b2,
                                          float* __restrict__ out,
                                          unsigned short* __restrict__ xn2b) {
    __shared__ float sl[16][64], al[16][64];
    __shared__ float mia[64];
    __shared__ float red[8];
    __shared__ float mkf[256];
    const int token = blockIdx.x, tid = threadIdx.x;
    const int b = token >> 8;
    const int l16 = tid & 15, jo = tid >> 4;
    mkf[tid] = (mask[b * 256 + tid] != 0) ? 1.0f : 0.0f;
    __syncthreads();

    float s0 = 0, s1 = 0, s2 = 0, s3 = 0;
    float a0 = 0, a1 = 0, a2 = 0, a3 = 0;
    const size_t ub = (size_t)token * (256 * 16);
    const size_t vb = (size_t)b * (256 * 16);
#pragma unroll 8
    for (int j = jo; j < 256; j += 16) {
        float4 u = U4[ub + (size_t)j * 16 + l16];
        ushort4 vv4 = V4b[vb + (size_t)j * 16 + l16];
        float mw = mkf[j];
        float w;
        w = __expf(u.x) * mw; s0 += w; a0 = fmaf(w, bf2f(vv4.x), a0);
        w = __expf(u.y) * mw; s1 += w; a1 = fmaf(w, bf2f(vv4.y), a1);
        w = __expf(u.z) * mw; s2 += w; a2 = fmaf(w, bf2f(vv4.z), a2);
        w = __expf(u.w) * mw; s3 += w; a3 = fmaf(w, bf2f(vv4.w), a3);
    }
    sl[jo][l16 * 4 + 0] = s0; sl[jo][l16 * 4 + 1] = s1;
    sl[jo][l16 * 4 + 2] = s2; sl[jo][l16 * 4 + 3] = s3;
    al[jo][l16 * 4 + 0] = a0; al[jo][l16 * 4 + 1] = a1;
    al[jo][l16 * 4 + 2] = a2; al[jo][l16 * 4 + 3] = a3;
    __syncthreads();
    if (tid < 64) {
        float S = 0, A = 0;
#pragma unroll
        for (int p = 0; p < 16; ++p) { S += sl[p][tid]; A += al[p][tid]; }
        mia[tid] = A / S;
    }
    __syncthreads();

    float r = x[(size_t)token * 256 + tid];
#pragma unroll 8
    for (int c = 0; c < 64; ++c)
        r = fmaf(mia[c], bf2f(Wob[(size_t)c * 256 + tid]), r);
    out[(size_t)token * 256 + tid] = r + b2[tid];
    float mu, rs;
    block_ln_stats(r, tid, red, mu, rs);
    xn2b[(size_t)token * 256 + tid] = f2bf((r - mu) * rs * gf[tid] + bf[tid]);
}

// ---------- kC2m: Aact = gelu(xn2b @ W1 + b1), 128x64 tile, BK=128 (2 iters) ----------
__global__ __launch_bounds__(256) void kC2m(const unsigned short* __restrict__ A,
                                            const unsigned short* __restrict__ Bt,
                                            const float* __restrict__ b1,
                                            unsigned short* __restrict__ Aact) {
    __shared__ __align__(16) unsigned short As[128][136];
    __shared__ __align__(16) unsigned short Bs[64][136];
    const int tid = threadIdx.x;
    const int tileM = blockIdx.y * 128, tileN = blockIdx.x * 64;
    const int w = tid >> 6, lane = tid & 63;
    const int waveM = w >> 1, waveN = w & 1;
    const int fr = lane & 15, fg = lane >> 4;
    f32x4 acc[4][2] = {};
    for (int kc = 0; kc < 256; kc += 128) {
#pragma unroll
        for (int h = 0; h < 8; ++h) {
            int idx = tid + h * 256;
            int row = idx >> 4, seg = idx & 15;
            *(uint4*)&As[row][seg * 8] =
                *(const uint4*)&A[(size_t)(tileM + row) * 256 + kc + seg * 8];
        }
#pragma unroll
        for (int h = 0; h < 4; ++h) {
            int idx = tid + h * 256;
            int row = idx >> 4, seg = idx & 15;
            *(uint4*)&Bs[row][seg * 8] =
                *(const uint4*)&Bt[(size_t)(tileN + row) * 256 + kc + seg * 8];
        }
        __syncthreads();
        bf16x8 a[4][4], b[2][4];
#pragma unroll
        for (int m = 0; m < 4; ++m)
#pragma unroll
            for (int k = 0; k < 4; ++k)
                a[m][k] = *(const bf16x8*)&As[waveM * 64 + m * 16 + fr][k * 32 + fg * 8];
#pragma unroll
        for (int n = 0; n < 2; ++n)
#pragma unroll
            for (int k = 0; k < 4; ++k)
                b[n][k] = *(const bf16x8*)&Bs[waveN * 32 + n * 16 + fr][k * 32 + fg * 8];
#pragma unroll
        for (int k = 0; k < 4; ++k)
#pragma unroll
            for (int m = 0; m < 4; ++m)
#pragma unroll
                for (int n = 0; n < 2; ++n)
                    acc[m][n] = __builtin_amdgcn_mfma_f32_16x16x32_bf16(
                        a[m][k], b[n][k], acc[m][n], 0, 0, 0);
        __syncthreads();
    }
#pragma unroll
    for (int m = 0; m < 4; ++m)
#pragma unroll
        for (int n = 0; n < 2; ++n) {
            int col = tileN + waveN * 32 + n * 16 + fr;
            float bb = b1[col];
#pragma unroll
            for (int r = 0; r < 4; ++r) {
                int row = tileM + waveM * 64 + m * 16 + fg * 4 + r;
                float v = acc[m][n][r] + bb;
                Aact[(size_t)row * 1024 + col] = f2bf(gelu_exact(v));
            }
        }
}

// ---------- kC3m: out += Aact @ W2 (split-K x2, atomicAdd), BK=128 (4 iters) ----------
__global__ __launch_bounds__(256) void kC3m(const unsigned short* __restrict__ A,
                                            const unsigned short* __restrict__ Bt,
                                            float* __restrict__ out) {
    __shared__ __align__(16) unsigned short As[64][136];
    __shared__ __align__(16) unsigned short Bs[64][136];
    const int tid = threadIdx.x;
    const int tileM = blockIdx.y * 64, tileN = blockIdx.x * 64;
    const int k0 = blockIdx.z * 512;
    const int w = tid >> 6, lane = tid & 63;
    const int waveM = w >> 1, waveN = w & 1;
    const int fr = lane & 15, fg = lane >> 4;
    f32x4 acc[2][2] = {};
    for (int kc = k0; kc < k0 + 512; kc += 128) {
#pragma unroll
        for (int h = 0; h < 4; ++h) {
            int idx = tid + h * 256;
            int row = idx >> 4, seg = idx & 15;
            *(uint4*)&As[row][seg * 8] =
                *(const uint4*)&A[(size_t)(tileM + row) * 1024 + kc + seg * 8];
        }
#pragma unroll
        for (int h = 0; h < 4; ++h) {
            int idx = tid + h * 256;
            int row = idx >> 4, seg = idx & 15;
            *(uint4*)&Bs[row][seg * 8] =
                *(const uint4*)&Bt[(size_t)(tileN + row) * 1024 + kc + seg * 8];
        }
        __syncthreads();
        bf16x8 a[2][4], b[2][4];
#pragma unroll
        for (int m = 0; m < 2; ++m)
#pragma unroll
            for (int k = 0; k < 4; ++k)
                a[m][k] = *(const bf16x8*)&As[waveM * 32 + m * 16 + fr][k * 32 + fg * 8];
#pragma unroll
        for (int n = 0; n < 2; ++n)
#pragma unroll
            for (int k = 0; k < 4; ++k)
                b[n][k] = *(const bf16x8*)&Bs[waveN * 32 + n * 16 + fr][k * 32 + fg * 8];
#pragma unroll
        for (int k = 0; k < 4; ++k)
#pragma unroll
            for (int m = 0; m < 2; ++m)
#pragma unroll
                for (int n = 0; n < 2; ++n)
                    acc[m][n] = __builtin_amdgcn_mfma_f32_16x16x32_bf16(
                        a[m][k], b[n][k], acc[m][n], 0, 0, 0);
        __syncthreads();
    }
#pragma unroll
    for (int m = 0; m < 2; ++m)
#pragma unroll
        for (int n = 0; n < 2; ++n) {
            int col = tileN + waveN * 32 + n * 16 + fr;
#pragma unroll
            for (int r = 0; r < 4; ++r) {
                int row = tileM + waveM * 32 + m * 16 + fg * 4 + r;
                atomicAdd(&out[(size_t)row * 256 + col], acc[m][n][r]);
            }
        }
}

extern "C" void kernel_launch(void* const* d_in, const int* in_sizes, int n_in,
                              void* d_out, int out_size, void* d_ws, size_t ws_size,
                              hipStream_t stream) {
    const float* x = (const float*)d_in[0];
    const float* U1 = (const float*)d_in[1];
    const int* mask = (const int*)d_in[2];
    const float* ln_mia_g = (const float*)d_in[3];
    const float* ln_mia_b = (const float*)d_in[4];
    const float* Wv = (const float*)d_in[5];
    const float* Wo = (const float*)d_in[6];
    const float* ln_ffn_g = (const float*)d_in[7];
    const float* ln_ffn_b = (const float*)d_in[8];
    const float* W1 = (const float*)d_in[9];
    const float* b1 = (const float*)d_in[10];
    const float* W2 = (const float*)d_in[11];
    const float* b2 = (const float*)d_in[12];
    float* out = (float*)d_out;

    char* ws = (char*)d_ws;
    unsigned short* Vb   = (unsigned short*)(ws);                             // 512 KB
    unsigned short* xn2b = (unsigned short*)(ws + (1u << 20));                // 2 MB
    unsigned short* W1t  = (unsigned short*)(ws + (3u << 20));                // 512 KB
    unsigned short* W2t  = (unsigned short*)(ws + (3u << 20) + (512u << 10)); // 512 KB
    unsigned short* Wob  = (unsigned short*)(ws + (4u << 20));                // 32 KB
    unsigned short* Aact = (unsigned short*)(ws + (5u << 20));                // 8 MB

    kATT<<<1032, 256, 0, stream>>>(x, ln_mia_g, ln_mia_b, Wv, Vb,
                                   W1, W1t, W2, W2t, Wo, Wob);
    kB<<<4096, 256, 0, stream>>>(x, (const float4*)U1, mask, (const ushort4*)Vb,
                                 Wob, ln_ffn_g, ln_ffn_b, b2, out, xn2b);
    kC2m<<<dim3(16, 32), 256, 0, stream>>>(xn2b, W1t, b1, Aact);
    kC3m<<<dim3(4, 64, 2), 256, 0, stream>>>(Aact, W2t, out);
}